// Round 11
// baseline (3231.200 us; speedup 1.0000x reference)
//
#include <hip/hip_runtime.h>
#include <float.h>
#include <math.h>

#define H      1024
#define SLEN   128
#define VOUT   32000
#define NSTEP  51
#define EOS_ID 2
#define NB     256
#define BT     1024
#define NWAVES 16
#define NENC   64      // encoder/decoder publisher-core blocks
#define UPB    16      // units per publisher block (H/NENC)
#define HROWS  4       // ht_new rows per block (4b..4b+3)
#define LROWS  125     // VOUT/NB logits rows per block
#define TOKS_OFF 51
#define QTAB_BYTES (LROWS*H)   // 128000 B dynamic LDS: int8 W_lt rows

typedef float fv4 __attribute__((ext_vector_type(4)));

// encoder hidden states: single-use tagged slots (tag t+1), never overwritten
__device__ unsigned long long g_hs[SLEN][H];
// decode exchange: parity double-buffered tagged slots (proven R8-R10 protocol)
struct Xch {
  unsigned long long h [2][H];
  unsigned long long ht[2][H];
  unsigned long long sc[2][SLEN];
  unsigned long long pv[2][NB];
};
__device__ Xch g_x;

__device__ __forceinline__ float wredsum(float v){
  v += __shfl_xor(v, 32, 64);
  v += __shfl_xor(v, 16, 64);
  v += __shfl_xor(v,  8, 64);
  v += __shfl_xor(v,  4, 64);
  v += __shfl_xor(v,  2, 64);
  v += __shfl_xor(v,  1, 64);
  return v;
}
__device__ __forceinline__ float wredmax(float v){
  v = fmaxf(v, __shfl_xor(v, 32, 64));
  v = fmaxf(v, __shfl_xor(v, 16, 64));
  v = fmaxf(v, __shfl_xor(v,  8, 64));
  v = fmaxf(v, __shfl_xor(v,  4, 64));
  v = fmaxf(v, __shfl_xor(v,  2, 64));
  v = fmaxf(v, __shfl_xor(v,  1, 64));
  return v;
}
__device__ __forceinline__ float sigm(float x){ return 1.0f/(1.0f+expf(-x)); }

__device__ __forceinline__ unsigned long long pollraw(const unsigned long long* p, unsigned tag){
  unsigned long long v = __hip_atomic_load(p, __ATOMIC_RELAXED, __HIP_MEMORY_SCOPE_AGENT);
  while((unsigned)(v & 0xffull) != tag){
    __builtin_amdgcn_s_sleep(1);
    v = __hip_atomic_load(p, __ATOMIC_RELAXED, __HIP_MEMORY_SCOPE_AGENT);
  }
  return v;
}
__device__ __forceinline__ float pollf(const unsigned long long* p, unsigned tag){
  return __uint_as_float((unsigned)(pollraw(p, tag) >> 32));
}
__device__ __forceinline__ float loadpay(const unsigned long long* p){
  return __uint_as_float((unsigned)(__hip_atomic_load(p, __ATOMIC_RELAXED,
                                    __HIP_MEMORY_SCOPE_AGENT) >> 32));
}
__device__ __forceinline__ void pubf(unsigned long long* p, float x, unsigned tag){
  __hip_atomic_store(p, (((unsigned long long)__float_as_uint(x))<<32) | (unsigned long long)tag,
                     __ATOMIC_RELAXED, __HIP_MEMORY_SCOPE_AGENT);
}
__device__ __forceinline__ void pubpv(unsigned long long* p, float v, int idx, unsigned tag){
  unsigned long long lo = (((unsigned long long)(unsigned)idx) << 8) | (unsigned long long)tag;
  __hip_atomic_store(p, (((unsigned long long)__float_as_uint(v))<<32) | lo,
                     __ATOMIC_RELAXED, __HIP_MEMORY_SCOPE_AGENT);
}

// per-lane partial dot of a 1024-long row (16 elems/lane as 4x float4)
__device__ __forceinline__ float partdot(const float* __restrict__ a,
                                         const float* __restrict__ hp, int lane){
  const float4* a4 = (const float4*)a;
  const float4* h4 = (const float4*)hp;
  float s = 0.f;
#pragma unroll
  for(int k=0;k<4;k++){
    float4 x = a4[lane + 64*k];
    float4 y = h4[lane + 64*k];
    s = fmaf(x.x,y.x,s); s = fmaf(x.y,y.y,s);
    s = fmaf(x.z,y.z,s); s = fmaf(x.w,y.w,s);
  }
  return s;
}
// same FMA order, h read from tagged g_hs column (payload extraction)
__device__ __forceinline__ float partdot_g64(const float* __restrict__ a,
                                             const unsigned long long* __restrict__ col,
                                             int lane){
  const float4* a4 = (const float4*)a;
  float s = 0.f;
#pragma unroll
  for(int k=0;k<4;k++){
    float4 x = a4[lane + 64*k];
    const unsigned long long* cp = col + 4*(lane + 64*k);
    float y0=loadpay(cp), y1=loadpay(cp+1), y2=loadpay(cp+2), y3=loadpay(cp+3);
    s = fmaf(x.x,y0,s); s = fmaf(x.y,y1,s);
    s = fmaf(x.z,y2,s); s = fmaf(x.w,y3,s);
  }
  return s;
}
// identical FMA order, nontemporal (one-time streams / rescue rows)
__device__ __forceinline__ float partdot_nt(const float* __restrict__ a,
                                            const float* __restrict__ hp, int lane){
  const fv4* a4 = (const fv4*)a;
  const float4* h4 = (const float4*)hp;
  float s = 0.f;
#pragma unroll
  for(int k=0;k<4;k++){
    fv4 x = __builtin_nontemporal_load(a4 + lane + 64*k);
    float4 y = h4[lane + 64*k];
    s = fmaf(x.x,y.x,s); s = fmaf(x.y,y.y,s);
    s = fmaf(x.z,y.z,s); s = fmaf(x.w,y.w,s);
  }
  return s;
}

// int8x4 dot with float4 (little-endian byte k = element k)
__device__ __forceinline__ float dotq(unsigned u, float4 hv, float acc){
  acc = fmaf((float)((int)(u<<24)>>24), hv.x, acc);
  acc = fmaf((float)((int)(u<<16)>>24), hv.y, acc);
  acc = fmaf((float)((int)(u<< 8)>>24), hv.z, acc);
  acc = fmaf((float)((int) u     >>24), hv.w, acc);
  return acc;
}

extern "C" __global__ void __launch_bounds__(BT)
nmt_kernel(const int* __restrict__ src_ids,
           const float* __restrict__ embed_input,
           const float* __restrict__ W_ih_e, const float* __restrict__ W_hh_e,
           const float* __restrict__ b_ih_e, const float* __restrict__ b_hh_e,
           const float* __restrict__ W_li,  const float* __restrict__ b_li,
           const float* __restrict__ embed_target,
           const float* __restrict__ W_ih_d, const float* __restrict__ W_hh_d,
           const float* __restrict__ b_ih_d, const float* __restrict__ b_hh_d,
           const float* __restrict__ W_lt,  const float* __restrict__ b_lt,
           const float* __restrict__ W_tl,  const float* __restrict__ b_tl,
           float* __restrict__ out)
{
  const int tid  = threadIdx.x;
  const int b    = blockIdx.x;
  const int w    = tid >> 6;
  const int lane = tid & 63;
  const bool pub = (b < NENC);   // block-uniform

  extern __shared__ __align__(16) char qmem[];       // 128000 B int8 table
  uint4* qtab = (uint4*)qmem;                        // row j: qtab[j*64 + lane]

  __shared__ __align__(16) float hbuf[H];
  __shared__ __align__(16) float hsrow[H];
  __shared__ __align__(16) float htn_lds[H];
  __shared__ __align__(16) float Mloc[HROWS][SLEN];
  __shared__ __align__(16) float sraw[SLEN];
  __shared__ __align__(16) float vloc[128];
  __shared__ __align__(16) float qrho[128];
  __shared__ __align__(16) float qinv[128];
  __shared__ __align__(16) float qbias[128];
  __shared__ int   rlist[128];
  __shared__ float gw[4][UPB];     // [gate][unit offset]
  __shared__ float c16[UPB];       // private cell state of owned units
  __shared__ float hn2[NWAVES];
  __shared__ float wred2[4];
  __shared__ float redv[NWAVES];
  __shared__ int   redi[NWAVES];
  __shared__ float gwhh_l[NWAVES][4];
  __shared__ int   wid_sh, done_sh;
  __shared__ float e_sh, rhomax_sh;
  __shared__ int   rcnt_sh;

// pv poll+reduce on waves 4..7 (concurrent with ht_new on waves 0..3)
#define PVPOLL47(TAG) do{                                                      \
    if(w>=4 && w<8){                                                           \
      unsigned long long v = pollraw(&g_x.pv[(TAG)&1][((w-4)<<6)+lane], (TAG));\
      float val = __uint_as_float((unsigned)(v>>32));                          \
      int   idx = (int)((unsigned)(v>>8) & 0xffffffu);                         \
      _Pragma("unroll")                                                        \
      for(int dd=32; dd>=1; dd>>=1){                                           \
        float ov=__shfl_xor(val,dd,64); int oi=__shfl_xor(idx,dd,64);          \
        if(ov>val || (ov==val && oi<idx)){ val=ov; idx=oi; }                   \
      }                                                                        \
      if(lane==0){ redv[w]=val; redi[w]=idx; }                                 \
    }                                                                          \
  }while(0)

  // one-time int8 quantization of this block's 125 W_lt rows (block-local)
  auto do_quant = [&](){
    const int rbase = b*LROWS;
#pragma unroll
    for(int t=0;t<8;t++){
      const int j = w + NWAVES*t;
      if(j < LROWS){
        const fv4* wr = (const fv4*)(W_lt + (size_t)(rbase+j)*H);
        fv4 g0=__builtin_nontemporal_load(wr+lane);
        fv4 g1=__builtin_nontemporal_load(wr+lane+64);
        fv4 g2=__builtin_nontemporal_load(wr+lane+128);
        fv4 g3=__builtin_nontemporal_load(wr+lane+192);
        float4 f0={g0.x,g0.y,g0.z,g0.w}, f1={g1.x,g1.y,g1.z,g1.w};
        float4 f2={g2.x,g2.y,g2.z,g2.w}, f3={g3.x,g3.y,g3.z,g3.w};
        float m;
        m = fmaxf(fabsf(f0.x),fabsf(f0.y)); m=fmaxf(m,fmaxf(fabsf(f0.z),fabsf(f0.w)));
        m = fmaxf(m,fmaxf(fabsf(f1.x),fabsf(f1.y))); m=fmaxf(m,fmaxf(fabsf(f1.z),fabsf(f1.w)));
        m = fmaxf(m,fmaxf(fabsf(f2.x),fabsf(f2.y))); m=fmaxf(m,fmaxf(fabsf(f2.z),fabsf(f2.w)));
        m = fmaxf(m,fmaxf(fabsf(f3.x),fabsf(f3.y))); m=fmaxf(m,fmaxf(fabsf(f3.z),fabsf(f3.w)));
        m = wredmax(m);
        const float s    = (m>1e-30f) ? 127.0f/m : 0.f;
        const float invs = (m>1e-30f) ? m*(1.0f/127.0f) : 0.f;
        float rsq = 0.f;
        unsigned pk[4];
        float4 ff[4] = {f0,f1,f2,f3};
#pragma unroll
        for(int u=0;u<4;u++){
          int q0=(int)rintf(ff[u].x*s), q1=(int)rintf(ff[u].y*s);
          int q2=(int)rintf(ff[u].z*s), q3=(int)rintf(ff[u].w*s);
          float d0=ff[u].x-(float)q0*invs, d1=ff[u].y-(float)q1*invs;
          float d2=ff[u].z-(float)q2*invs, d3=ff[u].w-(float)q3*invs;
          rsq=fmaf(d0,d0,rsq); rsq=fmaf(d1,d1,rsq);
          rsq=fmaf(d2,d2,rsq); rsq=fmaf(d3,d3,rsq);
          pk[u] = ((unsigned)(q0&255)) | ((unsigned)(q1&255)<<8)
                | ((unsigned)(q2&255)<<16) | ((unsigned)(q3&255)<<24);
        }
        uint4 qq; qq.x=pk[0]; qq.y=pk[1]; qq.z=pk[2]; qq.w=pk[3];
        qtab[j*64 + lane] = qq;
        rsq = wredsum(rsq);
        if(lane==0){
          qrho[j]  = sqrtf(rsq)*1.0002f + 1e-8f;
          qinv[j]  = invs;
          qbias[j] = b_lt[rbase+j];
        }
      }
    }
    __syncthreads();
    {
      float rv = (tid<LROWS) ? qrho[tid] : 0.f;
      if(tid<128){
        float m = wredmax(rv);
        if(lane==0) wred2[w]=m;
      }
    }
    __syncthreads();
    if(tid==0) rhomax_sh = fmaxf(wred2[0], wred2[1]);
    __syncthreads();
  };

  // ---- init ----
  hbuf[tid] = 0.f;
  if(tid<UPB) c16[tid] = 0.f;
  __syncthreads();

  if(pub){
    // ---- Xenc precompute: 4 rows/wave, kept in registers (xv0/xv1 + shfl) ----
    float xv0[4], xv1[4];
#pragma unroll
    for(int i=0;i<4;i++){
      const int row = (w>>2)*H + UPB*b + 4*(w&3) + i;
      const float4* wr = (const float4*)(W_ih_e + (size_t)row*H);
      float4 w0=wr[lane], w1=wr[lane+64], w2=wr[lane+128], w3=wr[lane+192];
      const float bias = b_ih_e[row] + b_hh_e[row];
      for(int t=0;t<SLEN;t+=2){
        const float4* xr = (const float4*)(embed_input + (size_t)src_ids[t]*H);
        const float4* yr = (const float4*)(embed_input + (size_t)src_ids[t+1]*H);
        float4 x0=xr[lane], x1=xr[lane+64], x2=xr[lane+128], x3=xr[lane+192];
        float4 y0=yr[lane], y1=yr[lane+64], y2=yr[lane+128], y3=yr[lane+192];
        float s, u;
        s = w0.x*x0.x;        s = fmaf(w0.y,x0.y,s); s = fmaf(w0.z,x0.z,s); s = fmaf(w0.w,x0.w,s);
        u = w0.x*y0.x;        u = fmaf(w0.y,y0.y,u); u = fmaf(w0.z,y0.z,u); u = fmaf(w0.w,y0.w,u);
        s = fmaf(w1.x,x1.x,s); s = fmaf(w1.y,x1.y,s); s = fmaf(w1.z,x1.z,s); s = fmaf(w1.w,x1.w,s);
        u = fmaf(w1.x,y1.x,u); u = fmaf(w1.y,y1.y,u); u = fmaf(w1.z,y1.z,u); u = fmaf(w1.w,y1.w,u);
        s = fmaf(w2.x,x2.x,s); s = fmaf(w2.y,x2.y,s); s = fmaf(w2.z,x2.z,s); s = fmaf(w2.w,x2.w,s);
        u = fmaf(w2.x,y2.x,u); u = fmaf(w2.y,y2.y,u); u = fmaf(w2.z,y2.z,u); u = fmaf(w2.w,y2.w,u);
        s = fmaf(w3.x,x3.x,s); s = fmaf(w3.y,x3.y,s); s = fmaf(w3.w,x3.w,s); s = fmaf(w3.z,x3.z,s);
        u = fmaf(w3.x,y3.x,u); u = fmaf(w3.y,y3.y,u); u = fmaf(w3.w,y3.w,u); u = fmaf(w3.z,y3.z,u);
        s = wredsum(s); u = wredsum(u);
        if(t < 64){
          if(lane==(t&63))     xv0[i] = s + bias;
          if(lane==((t+1)&63)) xv0[i] = u + bias;   // t,t+1 same half
        }else{
          if(lane==(t&63))     xv1[i] = s + bias;
          if(lane==((t+1)&63)) xv1[i] = u + bias;
        }
      }
    }
    __syncthreads();

    // ---- encoder: 128 steps, 64-block publisher core only ----
    for(int t=0;t<SLEN;t++){
      float sg[4];
#pragma unroll
      for(int i=0;i<4;i++){
        const int row = (w>>2)*H + UPB*b + 4*(w&3) + i;
        sg[i] = wredsum(partdot(W_hh_e + (size_t)row*H, hbuf, lane));
      }
#pragma unroll
      for(int i=0;i<4;i++){
        float xh = (t<64) ? xv0[i] : xv1[i];
        float xi = __shfl(xh, t&63, 64);
        if(lane==0) gw[w>>2][4*(w&3)+i] = sg[i] + xi;
      }
      __syncthreads();
      if(tid<UPB){
        float gi=gw[0][tid], gf=gw[1][tid], gg=gw[2][tid], go=gw[3][tid];
        float ii=sigm(gi), ff=sigm(gf), g2=tanhf(gg), oo=sigm(go);
        float c2=fmaf(ff, c16[tid], ii*g2);
        c16[tid]=c2;
        pubf(&g_hs[t][UPB*b+tid], oo*tanhf(c2), (unsigned)(t+1));
      }
      hbuf[tid] = pollf(&g_hs[t][tid], (unsigned)(t+1));
      __syncthreads();
    }
    // post-encoder: hsrow (b<64<128) + own Mloc from committed g_hs
    hsrow[tid] = loadpay(&g_hs[b][tid]);
    {
      const int r = w&3, c0 = (w>>2)*32;
      for(int cc=0;cc<32;cc++){
        const int col = c0+cc;
        float s = wredsum(partdot_g64(W_tl + (size_t)(4*b+r)*2*H, g_hs[col], lane));
        if(lane==0) Mloc[r][col]=s;
      }
    }
    __syncthreads();
    do_quant();
  } else {
    // consumers: quantize during the encoder, then drain g_hs in 8-col chunks
    do_quant();
    for(int c=0;c<16;c++){
      const int tl = 8*c+7;
      unsigned long long sv = pollraw(&g_hs[tl][tid], (unsigned)(tl+1));
      for(int cc=0;cc<8;cc++){
        const int col = 8*c+cc;
        float hv;
        if(cc<7) hv = loadpay(&g_hs[col][tid]);   // committed (sentinel transitivity)
        else     hv = __uint_as_float((unsigned)(sv>>32));
        hbuf[tid]=hv;
        __syncthreads();
        if(b==col) hsrow[tid]=hbuf[tid];
        if(w<HROWS){
          float s2 = wredsum(partdot(W_tl + (size_t)(4*b+w)*2*H, hbuf, lane));
          if(lane==0) Mloc[w][col]=s2;
        }
        __syncthreads();
      }
    }
  }
  // here: all blocks have hbuf = hs_all[127], Mloc, hsrow (b<128), qtab

  // ---- wid0 = argmax(W_li . hs + b_li) ----
  {
    float bestv=-FLT_MAX; int besti=0;
    for(int j=w; j<LROWS; j+=NWAVES){
      const int r = b*LROWS + j;
      float s = wredsum(partdot_nt(W_li + (size_t)r*H, hbuf, lane));
      if(lane==0){
        float v = s + b_li[r];
        if(v>bestv){ bestv=v; besti=r; }
      }
    }
    if(lane==0){ redv[w]=bestv; redi[w]=besti; }
    __syncthreads();
    if(tid==0){
      float bv=redv[0]; int bi=redi[0];
      for(int i=1;i<NWAVES;i++)
        if(redv[i]>bv || (redv[i]==bv && redi[i]<bi)){ bv=redv[i]; bi=redi[i]; }
      pubpv(&g_x.pv[1][b], bv, bi, 1u);
    }
  }
  __syncthreads();
  PVPOLL47(1u);
  __syncthreads();
  if(tid==0){
    float bv=redv[4]; int bi=redi[4];
    for(int i=5;i<8;i++)
      if(redv[i]>bv || (redv[i]==bv && redi[i]<bi)){ bv=redv[i]; bi=redi[i]; }
    wid_sh = bi;
    done_sh = (bi==EOS_ID) ? 1 : 0;
  }
  __syncthreads();

  // ---- first decoder cell: h tag 129 (publisher core) ----
  if(pub){
    const float* tk = embed_target + (size_t)wid_sh*H;
#pragma unroll
    for(int i=0;i<4;i++){
      const int row = (w>>2)*H + UPB*b + 4*(w&3) + i;
      float s = partdot(W_ih_d + (size_t)row*H, tk, lane)
              + partdot(W_hh_d + (size_t)row*H, hbuf, lane);
      s = wredsum(s);
      if(lane==0) gw[w>>2][4*(w&3)+i] = s + b_ih_d[row] + b_hh_d[row];
    }
  }
  __syncthreads();
  if(pub && tid<UPB){
    float gi=gw[0][tid], gf=gw[1][tid], gg=gw[2][tid], go=gw[3][tid];
    float ii=sigm(gi), ff=sigm(gf), g2=tanhf(gg), oo=sigm(go);
    float c2=fmaf(ff, c16[tid], ii*g2);
    c16[tid]=c2;
    pubf(&g_x.h[1][UPB*b+tid], oo*tanhf(c2), 129u);
  }
  hbuf[tid] = pollf(&g_x.h[1][tid], 129u);
  __syncthreads();
  if(b<SLEN && w==0){
    float s = wredsum(partdot(hsrow, hbuf, lane));
    if(lane==0) pubf(&g_x.sc[1][b], s, 1u);
  }
  if(pub){
#pragma unroll
    for(int i=0;i<4;i++){
      const int row = (w>>2)*H + UPB*b + 4*(w&3) + i;
      float s=wredsum(partdot(W_hh_d + (size_t)row*H, hbuf, lane));
      if(lane==0) gwhh_l[w][i]=s;
    }
  }
  __syncthreads();

  // ---- decode: 51 steps (R10 schedule; ownership remapped to 64 blocks) ----
  for(int k=0;k<NSTEP;k++){
    const unsigned htag = (unsigned)(130+k);
    const unsigned ttag = (unsigned)(k+1);
    // P1: sc poll
    if(tid<SLEN) sraw[tid] = pollf(&g_x.sc[ttag&1][tid], ttag);
    __syncthreads();
    // P2: softmax
    if(tid<SLEN){
      float m = wredmax(sraw[tid]);
      if(lane==0) wred2[w]=m;
    }
    __syncthreads();
    if(tid<SLEN){
      float mx=fmaxf(wred2[0],wred2[1]);
      float e=expf(sraw[tid]-mx);
      sraw[tid]=e;
      float z=wredsum(e);
      if(lane==0) wred2[2+w]=z;
    }
    __syncthreads();
    // P3: ht compute+pub (w0-3)  ||  pv poll (w4-7)
    if(w<HROWS){
      const int r=4*b+w;
      float invZ=1.f/(wred2[2]+wred2[3]);
      float att=fmaf(sraw[2*lane],Mloc[w][2*lane], sraw[2*lane+1]*Mloc[w][2*lane+1]);
      float s=partdot(W_tl + (size_t)r*2*H + H, hbuf, lane);
      float tot=wredsum(fmaf(att,invZ,s));
      if(lane==0) pubf(&g_x.ht[ttag&1][r], tanhf(tot + b_tl[r]), ttag);
    }
    if(k>0) PVPOLL47(ttag);
    __syncthreads();
    // P4: wid resolve + token out
    if(k>0 && tid==0){
      float bv=redv[4]; int bi=redi[4];
      for(int i=5;i<8;i++)
        if(redv[i]>bv || (redv[i]==bv && redi[i]<bi)){ bv=redv[i]; bi=redi[i]; }
      int iseos=(bi==EOS_ID)?1:0;
      if(b==0) out[k-1]=(float)((done_sh|iseos)?-1:bi);
      done_sh |= iseos;
      wid_sh = bi;
    }
    __syncthreads();
    // P5: decoder LSTM gates (publisher core, 4 rows/wave)
    if(pub){
      const float* tk=embed_target + (size_t)wid_sh*H;
#pragma unroll
      for(int i=0;i<4;i++){
        const int row = (w>>2)*H + UPB*b + 4*(w&3) + i;
        float s=wredsum(partdot(W_ih_d + (size_t)row*H, tk, lane));
        if(lane==0) gw[w>>2][4*(w&3)+i] = s + gwhh_l[w][i] + b_ih_d[row] + b_hh_d[row];
      }
    }
    __syncthreads();
    // P6: owner pointwise, publish new decoder h
    if(pub && tid<UPB){
      float gi=gw[0][tid], gf=gw[1][tid], gg=gw[2][tid], go=gw[3][tid];
      float ii=sigm(gi), ff=sigm(gf), g2=tanhf(gg), oo=sigm(go);
      float c2=fmaf(ff, c16[tid], ii*g2);
      c16[tid]=c2;
      pubf(&g_x.h[htag&1][UPB*b+tid], oo*tanhf(c2), htag);
    }
    // P7: poll ht (published P3 -> hits)
    htn_lds[tid] = pollf(&g_x.ht[ttag&1][tid], ttag);
    __syncthreads();
    // P8: ||h||^2 partials
    {
      float x = htn_lds[tid];
      float ss = wredsum(x*x);
      if(lane==0) hn2[w]=ss;
      if(tid==0) rcnt_sh=0;
    }
    __syncthreads();
    if(tid==0){
      float t2=0.f;
      for(int i=0;i<NWAVES;i++) t2+=hn2[i];
      float e = rhomax_sh * sqrtf(t2) * 1.0002f + 2e-3f;
      if(!(e>0.f && e<1e6f)) e=3.0e38f;
      e_sh = e;
    }
    // P9: int8 screen (conflict-free strided map)
    {
      const float4* h4=(const float4*)htn_lds;
      float4 h0=h4[lane], h1=h4[lane+64], h2=h4[lane+128], h3=h4[lane+192];
#pragma unroll
      for(int t=0;t<8;t++){
        const int j=w+NWAVES*t;
        if(j<LROWS){
          uint4 q = qtab[j*64 + lane];
          float acc=0.f;
          acc=dotq(q.x,h0,acc); acc=dotq(q.y,h1,acc);
          acc=dotq(q.z,h2,acc); acc=dotq(q.w,h3,acc);
          acc=wredsum(acc);
          if(lane==0) vloc[j] = acc*qinv[j] + qbias[j];
        }
      }
    }
    __syncthreads();
    // P10: logits out + block max
    {
      const size_t obase = TOKS_OFF + (size_t)k*VOUT + (size_t)b*LROWS;
      if(tid<LROWS) out[obase+tid]=vloc[tid];
      float mv=(tid<LROWS)?vloc[tid]:-FLT_MAX;
      if(tid<128){
        float m=wredmax(mv);
        if(lane==0) wred2[w]=m;
      }
    }
    __syncthreads();
    // P11: screen threshold -> rlist
    {
      float thr = fmaxf(wred2[0],wred2[1]) - 2.0f*e_sh;
      if(tid<LROWS && vloc[tid]>=thr){
        int pos=atomicAdd(&rcnt_sh,1);
        rlist[pos]=tid;
      }
    }
    __syncthreads();
    // P12: poll new h (published P6; P7-P11 covered RTT)
    hbuf[tid] = pollf(&g_x.h[htag&1][tid], htag);
    __syncthreads();
    // P13+P14: sc pub ASAP + gwhh prefetch + exact fp32 rescue
    if(b<SLEN && w==0){
      float s=wredsum(partdot(hsrow, hbuf, lane));
      if(lane==0) pubf(&g_x.sc[(k+2)&1][b], s, (unsigned)(k+2));
    }
    if(pub){
#pragma unroll
      for(int i=0;i<4;i++){
        const int row = (w>>2)*H + UPB*b + 4*(w&3) + i;
        float s=wredsum(partdot(W_hh_d + (size_t)row*H, hbuf, lane));
        if(lane==0) gwhh_l[w][i]=s;
      }
    }
    {
      float bestv=-FLT_MAX; int besti=0x7fffffff;
      const int nr=rcnt_sh;
      for(int s2=w;s2<nr;s2+=NWAVES){
        const int r=b*LROWS+rlist[s2];
        float s=wredsum(partdot_nt(W_lt + (size_t)r*H, htn_lds, lane));
        if(lane==0){
          float f=s+qbias[rlist[s2]];
          if(f>bestv || (f==bestv && r<besti)){ bestv=f; besti=r; }
        }
      }
      if(lane==0){ redv[w]=bestv; redi[w]=besti; }
    }
    __syncthreads();
    // P15: publish pv candidate
    if(tid==0){
      float bv=redv[0]; int bi=redi[0];
      for(int i=1;i<NWAVES;i++)
        if(redv[i]>bv || (redv[i]==bv && redi[i]<bi)){ bv=redv[i]; bi=redi[i]; }
      pubpv(&g_x.pv[(k+2)&1][b], bv, bi, (unsigned)(k+2));
    }
  }

  // ---- epilogue: last token ----
  if(b==0){
    PVPOLL47((unsigned)(NSTEP+1));
    __syncthreads();
    if(tid==0){
      float bv=redv[4]; int bi=redi[4];
      for(int i=5;i<8;i++)
        if(redv[i]>bv || (redv[i]==bv && redi[i]<bi)){ bv=redv[i]; bi=redi[i]; }
      int iseos=(bi==EOS_ID)?1:0;
      out[NSTEP-1]=(float)((done_sh|iseos)?-1:bi);
    }
  }
#undef PVPOLL47
}

extern "C" void kernel_launch(void* const* d_in, const int* in_sizes, int n_in,
                              void* d_out, int out_size, void* d_ws, size_t ws_size,
                              hipStream_t stream) {
  const int*   src_ids      = (const int*)  d_in[0];
  const float* embed_input  = (const float*)d_in[1];
  const float* W_ih_e       = (const float*)d_in[2];
  const float* W_hh_e       = (const float*)d_in[3];
  const float* b_ih_e       = (const float*)d_in[4];
  const float* b_hh_e       = (const float*)d_in[5];
  const float* W_li         = (const float*)d_in[6];
  const float* b_li         = (const float*)d_in[7];
  const float* embed_target = (const float*)d_in[8];
  const float* W_ih_d       = (const float*)d_in[9];
  const float* W_hh_d       = (const float*)d_in[10];
  const float* b_ih_d       = (const float*)d_in[11];
  const float* b_hh_d       = (const float*)d_in[12];
  const float* W_lt         = (const float*)d_in[13];
  const float* b_lt         = (const float*)d_in[14];
  const float* W_tl         = (const float*)d_in[15];
  const float* b_tl         = (const float*)d_in[16];
  float*       out          = (float*)d_out;

  // zero all tagged slots every launch (tag 0 matches nothing; capture-safe)
  void* sptr = nullptr;
  (void)hipGetSymbolAddress(&sptr, HIP_SYMBOL(g_x));
  if(sptr) (void)hipMemsetAsync(sptr, 0, sizeof(Xch), stream);
  void* hptr = nullptr;
  (void)hipGetSymbolAddress(&hptr, HIP_SYMBOL(g_hs));
  if(hptr) (void)hipMemsetAsync(hptr, 0, sizeof(unsigned long long)*SLEN*H, stream);

  void* args[] = {
    (void*)&src_ids, (void*)&embed_input,
    (void*)&W_ih_e, (void*)&W_hh_e, (void*)&b_ih_e, (void*)&b_hh_e,
    (void*)&W_li, (void*)&b_li, (void*)&embed_target,
    (void*)&W_ih_d, (void*)&W_hh_d, (void*)&b_ih_d, (void*)&b_hh_d,
    (void*)&W_lt, (void*)&b_lt, (void*)&W_tl, (void*)&b_tl,
    (void*)&out
  };

  hipError_t err = hipLaunchCooperativeKernel((const void*)nmt_kernel,
                                              dim3(NB), dim3(BT), args,
                                              QTAB_BYTES, stream);
  if (err != hipSuccess) {
    nmt_kernel<<<dim3(NB), dim3(BT), QTAB_BYTES, stream>>>(
        src_ids, embed_input, W_ih_e, W_hh_e, b_ih_e, b_hh_e,
        W_li, b_li, embed_target, W_ih_d, W_hh_d, b_ih_d, b_hh_d,
        W_lt, b_lt, W_tl, b_tl, out);
  }
}

// Round 12
// 2184.039 us; speedup vs baseline: 1.4795x; 1.4795x over previous
//
#include <hip/hip_runtime.h>
#include <float.h>
#include <math.h>

#define H      1024
#define SLEN   128
#define VOUT   32000
#define NSTEP  51
#define EOS_ID 2
#define NB     256
#define BT     1024
#define NWAVES 16
#define HROWS  4       // ht_new rows per block (4b..4b+3)
#define LROWS  125     // VOUT/NB logits rows per block
#define TOKS_OFF 51
#define QTAB_BYTES (LROWS*H)   // 128000 B dynamic LDS: int8 W_lt rows

typedef float fv4 __attribute__((ext_vector_type(4)));

// decode exchange: parity double-buffered tagged slots (proven R8-R10 protocol)
struct Xch {
  unsigned long long h [2][H];
  unsigned long long ht[2][H];
  unsigned long long sc[2][SLEN];
  unsigned long long pv[2][NB];
};
__device__ Xch g_x;
// kernel-boundary state (plain stores; visibility guaranteed at dispatch edge)
__device__ __align__(16) float g_hsall[SLEN][H];   // hs_all
__device__ __align__(16) float g_c[H];             // encoder cell state

__device__ __forceinline__ float wredsum(float v){
  v += __shfl_xor(v, 32, 64);
  v += __shfl_xor(v, 16, 64);
  v += __shfl_xor(v,  8, 64);
  v += __shfl_xor(v,  4, 64);
  v += __shfl_xor(v,  2, 64);
  v += __shfl_xor(v,  1, 64);
  return v;
}
__device__ __forceinline__ float wredmax(float v){
  v = fmaxf(v, __shfl_xor(v, 32, 64));
  v = fmaxf(v, __shfl_xor(v, 16, 64));
  v = fmaxf(v, __shfl_xor(v,  8, 64));
  v = fmaxf(v, __shfl_xor(v,  4, 64));
  v = fmaxf(v, __shfl_xor(v,  2, 64));
  v = fmaxf(v, __shfl_xor(v,  1, 64));
  return v;
}
__device__ __forceinline__ float sigm(float x){ return 1.0f/(1.0f+expf(-x)); }

__device__ __forceinline__ unsigned long long pollraw(const unsigned long long* p, unsigned tag){
  unsigned long long v = __hip_atomic_load(p, __ATOMIC_RELAXED, __HIP_MEMORY_SCOPE_AGENT);
  while((unsigned)(v & 0xffull) != tag){
    __builtin_amdgcn_s_sleep(1);
    v = __hip_atomic_load(p, __ATOMIC_RELAXED, __HIP_MEMORY_SCOPE_AGENT);
  }
  return v;
}
__device__ __forceinline__ float pollf(const unsigned long long* p, unsigned tag){
  return __uint_as_float((unsigned)(pollraw(p, tag) >> 32));
}
__device__ __forceinline__ void pubf(unsigned long long* p, float x, unsigned tag){
  __hip_atomic_store(p, (((unsigned long long)__float_as_uint(x))<<32) | (unsigned long long)tag,
                     __ATOMIC_RELAXED, __HIP_MEMORY_SCOPE_AGENT);
}
__device__ __forceinline__ void pubpv(unsigned long long* p, float v, int idx, unsigned tag){
  unsigned long long lo = (((unsigned long long)(unsigned)idx) << 8) | (unsigned long long)tag;
  __hip_atomic_store(p, (((unsigned long long)__float_as_uint(v))<<32) | lo,
                     __ATOMIC_RELAXED, __HIP_MEMORY_SCOPE_AGENT);
}

// per-lane partial dot of a 1024-long row (16 elems/lane as 4x float4)
__device__ __forceinline__ float partdot(const float* __restrict__ a,
                                         const float* __restrict__ hp, int lane){
  const float4* a4 = (const float4*)a;
  const float4* h4 = (const float4*)hp;
  float s = 0.f;
#pragma unroll
  for(int k=0;k<4;k++){
    float4 x = a4[lane + 64*k];
    float4 y = h4[lane + 64*k];
    s = fmaf(x.x,y.x,s); s = fmaf(x.y,y.y,s);
    s = fmaf(x.z,y.z,s); s = fmaf(x.w,y.w,s);
  }
  return s;
}
// identical FMA order, nontemporal (one-time streams / rescue rows)
__device__ __forceinline__ float partdot_nt(const float* __restrict__ a,
                                            const float* __restrict__ hp, int lane){
  const fv4* a4 = (const fv4*)a;
  const float4* h4 = (const float4*)hp;
  float s = 0.f;
#pragma unroll
  for(int k=0;k<4;k++){
    fv4 x = __builtin_nontemporal_load(a4 + lane + 64*k);
    float4 y = h4[lane + 64*k];
    s = fmaf(x.x,y.x,s); s = fmaf(x.y,y.y,s);
    s = fmaf(x.z,y.z,s); s = fmaf(x.w,y.w,s);
  }
  return s;
}

// int8x4 dot with float4 (little-endian byte k = element k)
__device__ __forceinline__ float dotq(unsigned u, float4 hv, float acc){
  acc = fmaf((float)((int)(u<<24)>>24), hv.x, acc);
  acc = fmaf((float)((int)(u<<16)>>24), hv.y, acc);
  acc = fmaf((float)((int)(u<< 8)>>24), hv.z, acc);
  acc = fmaf((float)((int) u     >>24), hv.w, acc);
  return acc;
}

// =================== kernel A: xenc + encoder (R10 structure) ===============
extern "C" __global__ void __launch_bounds__(BT)
nmt_enc(const int* __restrict__ src_ids,
        const float* __restrict__ embed_input,
        const float* __restrict__ W_ih_e, const float* __restrict__ W_hh_e,
        const float* __restrict__ b_ih_e, const float* __restrict__ b_hh_e)
{
  const int tid  = threadIdx.x;
  const int b    = blockIdx.x;
  const int w    = tid >> 6;
  const int lane = tid & 63;
  const int grow = (w>>2)*H + 4*b + (w&3);

  __shared__ __align__(16) float hbuf[H];
  __shared__ __align__(16) float xenc[SLEN][NWAVES];
  __shared__ float gw4[4][4];
  __shared__ float c4[4];

  hbuf[tid] = 0.f;
  if(tid<4) c4[tid] = 0.f;
  __syncthreads();

  // xenc precompute (2-token ILP; per-token FMA order unchanged)
  {
    const float4* wr = (const float4*)(W_ih_e + (size_t)grow*H);
    float4 w0=wr[lane], w1=wr[lane+64], w2=wr[lane+128], w3=wr[lane+192];
    const float bias = b_ih_e[grow] + b_hh_e[grow];
    for(int t=0;t<SLEN;t+=2){
      const float4* xr = (const float4*)(embed_input + (size_t)src_ids[t]*H);
      const float4* yr = (const float4*)(embed_input + (size_t)src_ids[t+1]*H);
      float4 x0=xr[lane], x1=xr[lane+64], x2=xr[lane+128], x3=xr[lane+192];
      float4 y0=yr[lane], y1=yr[lane+64], y2=yr[lane+128], y3=yr[lane+192];
      float s, u;
      s = w0.x*x0.x;        s = fmaf(w0.y,x0.y,s); s = fmaf(w0.z,x0.z,s); s = fmaf(w0.w,x0.w,s);
      u = w0.x*y0.x;        u = fmaf(w0.y,y0.y,u); u = fmaf(w0.z,y0.z,u); u = fmaf(w0.w,y0.w,u);
      s = fmaf(w1.x,x1.x,s); s = fmaf(w1.y,x1.y,s); s = fmaf(w1.z,x1.z,s); s = fmaf(w1.w,x1.w,s);
      u = fmaf(w1.x,y1.x,u); u = fmaf(w1.y,y1.y,u); u = fmaf(w1.z,y1.z,u); u = fmaf(w1.w,y1.w,u);
      s = fmaf(w2.x,x2.x,s); s = fmaf(w2.y,x2.y,s); s = fmaf(w2.z,x2.z,s); s = fmaf(w2.w,x2.w,s);
      u = fmaf(w2.x,y2.x,u); u = fmaf(w2.y,y2.y,u); u = fmaf(w2.z,y2.z,u); u = fmaf(w2.w,y2.w,u);
      s = fmaf(w3.x,x3.x,s); s = fmaf(w3.y,x3.y,s); s = fmaf(w3.w,x3.w,s); s = fmaf(w3.z,x3.z,s);
      u = fmaf(w3.x,y3.x,u); u = fmaf(w3.y,y3.y,u); u = fmaf(w3.w,y3.w,u); u = fmaf(w3.z,y3.z,u);
      s = wredsum(s); u = wredsum(u);
      if(lane==0){ xenc[t][w] = s + bias; xenc[t+1][w] = u + bias; }
    }
  }
  __syncthreads();

  // encoder: 128 steps; Mloc de-folded (moved to nmt_dec prologue)
  for(int t=0;t<SLEN;t++){
    {
      float s = wredsum(partdot(W_hh_e + (size_t)grow*H, hbuf, lane)) + xenc[t][w];
      if(lane==0) gw4[w>>2][w&3] = s;
    }
    __syncthreads();
    if(tid<4){
      float gi=gw4[0][tid], gf=gw4[1][tid], gg=gw4[2][tid], go=gw4[3][tid];
      float ii=sigm(gi), ff=sigm(gf), g2=tanhf(gg), oo=sigm(go);
      float c2=fmaf(ff, c4[tid], ii*g2);
      c4[tid]=c2;
      pubf(&g_x.h[(t+1)&1][4*b+tid], oo*tanhf(c2), (unsigned)(t+1));
    }
    hbuf[tid] = pollf(&g_x.h[(t+1)&1][tid], (unsigned)(t+1));
    __syncthreads();
    if(b==t) g_hsall[t][tid] = hbuf[tid];   // hs_all[t]; visible at kernel edge
  }
  if(tid<4) g_c[4*b+tid] = c4[tid];
}

// ============== kernel B: Mloc + quant + wid0 + decode (R10 schedule) =======
extern "C" __global__ void __launch_bounds__(BT)
nmt_dec(const float* __restrict__ W_li,  const float* __restrict__ b_li,
        const float* __restrict__ embed_target,
        const float* __restrict__ W_ih_d, const float* __restrict__ W_hh_d,
        const float* __restrict__ b_ih_d, const float* __restrict__ b_hh_d,
        const float* __restrict__ W_lt,  const float* __restrict__ b_lt,
        const float* __restrict__ W_tl,  const float* __restrict__ b_tl,
        float* __restrict__ out)
{
  const int tid  = threadIdx.x;
  const int b    = blockIdx.x;
  const int w    = tid >> 6;
  const int lane = tid & 63;
  const int grow = (w>>2)*H + 4*b + (w&3);

  extern __shared__ __align__(16) char qmem[];       // 128000 B int8 table
  uint4* qtab = (uint4*)qmem;                        // row j: qtab[j*64 + lane]

  __shared__ __align__(16) float hbuf[H];
  __shared__ __align__(16) float hsrow[H];
  __shared__ __align__(16) float htn_lds[H];
  __shared__ __align__(16) float Mloc[HROWS][SLEN];
  __shared__ __align__(16) float sraw[SLEN];
  __shared__ __align__(16) float vloc[128];
  __shared__ __align__(16) float qrho[128];
  __shared__ __align__(16) float qinv[128];
  __shared__ __align__(16) float qbias[128];
  __shared__ int   rlist[128];
  __shared__ float gw4[4][4];
  __shared__ float c4[4];
  __shared__ float hn2[NWAVES];
  __shared__ float wred2[4];
  __shared__ float redv[NWAVES];
  __shared__ int   redi[NWAVES];
  __shared__ float gwhh_l[NWAVES];
  __shared__ int   wid_sh, done_sh;
  __shared__ float e_sh, rhomax_sh;
  __shared__ int   rcnt_sh;

#define PVPOLL47(TAG) do{                                                      \
    if(w>=4 && w<8){                                                           \
      unsigned long long v = pollraw(&g_x.pv[(TAG)&1][((w-4)<<6)+lane], (TAG));\
      float val = __uint_as_float((unsigned)(v>>32));                          \
      int   idx = (int)((unsigned)(v>>8) & 0xffffffu);                         \
      _Pragma("unroll")                                                        \
      for(int dd=32; dd>=1; dd>>=1){                                           \
        float ov=__shfl_xor(val,dd,64); int oi=__shfl_xor(idx,dd,64);          \
        if(ov>val || (ov==val && oi<idx)){ val=ov; idx=oi; }                   \
      }                                                                        \
      if(lane==0){ redv[w]=val; redi[w]=idx; }                                 \
    }                                                                          \
  }while(0)

  // ---- prologue: restore state from kernel edge ----
  hbuf[tid] = g_hsall[SLEN-1][tid];
  if(b<SLEN) hsrow[tid] = g_hsall[b][tid];
  if(tid<4)  c4[tid] = g_c[4*b+tid];
  __syncthreads();
  // Mloc: 4 rows x 128 cols; wave w -> row w&3, cols (w>>2)*32.. (+31)
  // same partdot FMA order as R10's fold -> bit-identical values
  {
    const int r = w&3, cbase = (w>>2)*32;
    for(int cc=0;cc<32;cc++){
      const int col = cbase+cc;
      float s = wredsum(partdot(W_tl + (size_t)(4*b+r)*2*H, g_hsall[col], lane));
      if(lane==0) Mloc[r][col]=s;
    }
  }
  __syncthreads();

  // ---- one-time: quantize W_lt rows into LDS (int8), strided element map ----
  {
    const int rbase = b*LROWS;
#pragma unroll
    for(int t=0;t<8;t++){
      const int j = w + NWAVES*t;
      if(j < LROWS){
        const fv4* wr = (const fv4*)(W_lt + (size_t)(rbase+j)*H);
        fv4 g0=__builtin_nontemporal_load(wr+lane);
        fv4 g1=__builtin_nontemporal_load(wr+lane+64);
        fv4 g2=__builtin_nontemporal_load(wr+lane+128);
        fv4 g3=__builtin_nontemporal_load(wr+lane+192);
        float4 f0={g0.x,g0.y,g0.z,g0.w}, f1={g1.x,g1.y,g1.z,g1.w};
        float4 f2={g2.x,g2.y,g2.z,g2.w}, f3={g3.x,g3.y,g3.z,g3.w};
        float m;
        m = fmaxf(fabsf(f0.x),fabsf(f0.y)); m=fmaxf(m,fmaxf(fabsf(f0.z),fabsf(f0.w)));
        m = fmaxf(m,fmaxf(fabsf(f1.x),fabsf(f1.y))); m=fmaxf(m,fmaxf(fabsf(f1.z),fabsf(f1.w)));
        m = fmaxf(m,fmaxf(fabsf(f2.x),fabsf(f2.y))); m=fmaxf(m,fmaxf(fabsf(f2.z),fabsf(f2.w)));
        m = fmaxf(m,fmaxf(fabsf(f3.x),fabsf(f3.y))); m=fmaxf(m,fmaxf(fabsf(f3.z),fabsf(f3.w)));
        m = wredmax(m);
        const float s    = (m>1e-30f) ? 127.0f/m : 0.f;
        const float invs = (m>1e-30f) ? m*(1.0f/127.0f) : 0.f;
        float rsq = 0.f;
        unsigned pk[4];
        float4 ff[4] = {f0,f1,f2,f3};
#pragma unroll
        for(int u=0;u<4;u++){
          int q0=(int)rintf(ff[u].x*s), q1=(int)rintf(ff[u].y*s);
          int q2=(int)rintf(ff[u].z*s), q3=(int)rintf(ff[u].w*s);
          float d0=ff[u].x-(float)q0*invs, d1=ff[u].y-(float)q1*invs;
          float d2=ff[u].z-(float)q2*invs, d3=ff[u].w-(float)q3*invs;
          rsq=fmaf(d0,d0,rsq); rsq=fmaf(d1,d1,rsq);
          rsq=fmaf(d2,d2,rsq); rsq=fmaf(d3,d3,rsq);
          pk[u] = ((unsigned)(q0&255)) | ((unsigned)(q1&255)<<8)
                | ((unsigned)(q2&255)<<16) | ((unsigned)(q3&255)<<24);
        }
        uint4 qq; qq.x=pk[0]; qq.y=pk[1]; qq.z=pk[2]; qq.w=pk[3];
        qtab[j*64 + lane] = qq;
        rsq = wredsum(rsq);
        if(lane==0){
          qrho[j]  = sqrtf(rsq)*1.0002f + 1e-8f;
          qinv[j]  = invs;
          qbias[j] = b_lt[rbase+j];
        }
      }
    }
  }
  __syncthreads();
  {
    float rv = (tid<LROWS) ? qrho[tid] : 0.f;
    if(tid<128){
      float m = wredmax(rv);
      if(lane==0) wred2[w]=m;
    }
  }
  __syncthreads();
  if(tid==0) rhomax_sh = fmaxf(wred2[0], wred2[1]);

  // ---- wid0 = argmax(W_li . hs + b_li) ----
  {
    float bestv=-FLT_MAX; int besti=0;
    for(int j=w; j<LROWS; j+=NWAVES){
      const int r = b*LROWS + j;
      float s = wredsum(partdot_nt(W_li + (size_t)r*H, hbuf, lane));
      if(lane==0){
        float v = s + b_li[r];
        if(v>bestv){ bestv=v; besti=r; }
      }
    }
    if(lane==0){ redv[w]=bestv; redi[w]=besti; }
    __syncthreads();
    if(tid==0){
      float bv=redv[0]; int bi=redi[0];
      for(int i=1;i<NWAVES;i++)
        if(redv[i]>bv || (redv[i]==bv && redi[i]<bi)){ bv=redv[i]; bi=redi[i]; }
      pubpv(&g_x.pv[1][b], bv, bi, 1u);
    }
  }
  __syncthreads();
  PVPOLL47(1u);
  __syncthreads();
  if(tid==0){
    float bv=redv[4]; int bi=redi[4];
    for(int i=5;i<8;i++)
      if(redv[i]>bv || (redv[i]==bv && redi[i]<bi)){ bv=redv[i]; bi=redi[i]; }
    wid_sh = bi;
    done_sh = (bi==EOS_ID) ? 1 : 0;
  }
  __syncthreads();

  // ---- first decoder cell: h tag 129 ----
  {
    const float* tk = embed_target + (size_t)wid_sh*H;
    float s = partdot(W_ih_d + (size_t)grow*H, tk, lane)
            + partdot(W_hh_d + (size_t)grow*H, hbuf, lane);
    s = wredsum(s);
    if(lane==0) gw4[w>>2][w&3] = s + b_ih_d[grow] + b_hh_d[grow];
  }
  __syncthreads();
  if(tid<4){
    float gi=gw4[0][tid], gf=gw4[1][tid], gg=gw4[2][tid], go=gw4[3][tid];
    float ii=sigm(gi), ff=sigm(gf), g2=tanhf(gg), oo=sigm(go);
    float c2=fmaf(ff, c4[tid], ii*g2);
    c4[tid]=c2;
    pubf(&g_x.h[1][4*b+tid], oo*tanhf(c2), 129u);
  }
  hbuf[tid] = pollf(&g_x.h[1][tid], 129u);
  __syncthreads();
  if(b<SLEN && w==0){
    float s = wredsum(partdot(hsrow, hbuf, lane));
    if(lane==0) pubf(&g_x.sc[1][b], s, 1u);
  }
  {
    float s=wredsum(partdot(W_hh_d + (size_t)grow*H, hbuf, lane));
    if(lane==0) gwhh_l[w]=s;
  }
  __syncthreads();

  // ---- decode: 51 steps (R10 schedule verbatim) ----
  for(int k=0;k<NSTEP;k++){
    const unsigned htag = (unsigned)(130+k);
    const unsigned ttag = (unsigned)(k+1);
    // P1: sc poll
    if(tid<SLEN) sraw[tid] = pollf(&g_x.sc[ttag&1][tid], ttag);
    __syncthreads();
    // P2: softmax
    if(tid<SLEN){
      float m = wredmax(sraw[tid]);
      if(lane==0) wred2[w]=m;
    }
    __syncthreads();
    if(tid<SLEN){
      float mx=fmaxf(wred2[0],wred2[1]);
      float e=expf(sraw[tid]-mx);
      sraw[tid]=e;
      float z=wredsum(e);
      if(lane==0) wred2[2+w]=z;
    }
    __syncthreads();
    // P3: ht compute+pub (w0-3)  ||  pv poll (w4-7)
    if(w<HROWS){
      const int r=4*b+w;
      float invZ=1.f/(wred2[2]+wred2[3]);
      float att=fmaf(sraw[2*lane],Mloc[w][2*lane], sraw[2*lane+1]*Mloc[w][2*lane+1]);
      float s=partdot(W_tl + (size_t)r*2*H + H, hbuf, lane);
      float tot=wredsum(fmaf(att,invZ,s));
      if(lane==0) pubf(&g_x.ht[ttag&1][r], tanhf(tot + b_tl[r]), ttag);
    }
    if(k>0) PVPOLL47(ttag);
    __syncthreads();
    // P4: wid resolve + token out
    if(k>0 && tid==0){
      float bv=redv[4]; int bi=redi[4];
      for(int i=5;i<8;i++)
        if(redv[i]>bv || (redv[i]==bv && redi[i]<bi)){ bv=redv[i]; bi=redi[i]; }
      int iseos=(bi==EOS_ID)?1:0;
      if(b==0) out[k-1]=(float)((done_sh|iseos)?-1:bi);
      done_sh |= iseos;
      wid_sh = bi;
    }
    __syncthreads();
    // P5: decoder LSTM gates
    {
      const float* tk=embed_target + (size_t)wid_sh*H;
      float s=wredsum(partdot(W_ih_d + (size_t)grow*H, tk, lane));
      if(lane==0) gw4[w>>2][w&3] = s + gwhh_l[w] + b_ih_d[grow] + b_hh_d[grow];
    }
    __syncthreads();
    // P6: owner pointwise, publish new decoder h
    if(tid<4){
      float gi=gw4[0][tid], gf=gw4[1][tid], gg=gw4[2][tid], go=gw4[3][tid];
      float ii=sigm(gi), ff=sigm(gf), g2=tanhf(gg), oo=sigm(go);
      float c2=fmaf(ff, c4[tid], ii*g2);
      c4[tid]=c2;
      pubf(&g_x.h[htag&1][4*b+tid], oo*tanhf(c2), htag);
    }
    // P7: poll ht
    htn_lds[tid] = pollf(&g_x.ht[ttag&1][tid], ttag);
    __syncthreads();
    // P8: ||h||^2 partials
    {
      float x = htn_lds[tid];
      float ss = wredsum(x*x);
      if(lane==0) hn2[w]=ss;
      if(tid==0) rcnt_sh=0;
    }
    __syncthreads();
    if(tid==0){
      float t2=0.f;
      for(int i=0;i<NWAVES;i++) t2+=hn2[i];
      float e = rhomax_sh * sqrtf(t2) * 1.0002f + 2e-3f;
      if(!(e>0.f && e<1e6f)) e=3.0e38f;
      e_sh = e;
    }
    // P9: int8 screen (conflict-free strided map)
    {
      const float4* h4=(const float4*)htn_lds;
      float4 h0=h4[lane], h1=h4[lane+64], h2=h4[lane+128], h3=h4[lane+192];
#pragma unroll
      for(int t=0;t<8;t++){
        const int j=w+NWAVES*t;
        if(j<LROWS){
          uint4 q = qtab[j*64 + lane];
          float acc=0.f;
          acc=dotq(q.x,h0,acc); acc=dotq(q.y,h1,acc);
          acc=dotq(q.z,h2,acc); acc=dotq(q.w,h3,acc);
          acc=wredsum(acc);
          if(lane==0) vloc[j] = acc*qinv[j] + qbias[j];
        }
      }
    }
    __syncthreads();
    // P10: logits out + block max
    {
      const size_t obase = TOKS_OFF + (size_t)k*VOUT + (size_t)b*LROWS;
      if(tid<LROWS) out[obase+tid]=vloc[tid];
      float mv=(tid<LROWS)?vloc[tid]:-FLT_MAX;
      if(tid<128){
        float m=wredmax(mv);
        if(lane==0) wred2[w]=m;
      }
    }
    __syncthreads();
    // P11: screen threshold -> rlist
    {
      float thr = fmaxf(wred2[0],wred2[1]) - 2.0f*e_sh;
      if(tid<LROWS && vloc[tid]>=thr){
        int pos=atomicAdd(&rcnt_sh,1);
        rlist[pos]=tid;
      }
    }
    __syncthreads();
    // P12: poll new h
    hbuf[tid] = pollf(&g_x.h[htag&1][tid], htag);
    __syncthreads();
    // P13+P14: sc pub ASAP + gwhh prefetch + exact fp32 rescue
    if(b<SLEN && w==0){
      float s=wredsum(partdot(hsrow, hbuf, lane));
      if(lane==0) pubf(&g_x.sc[(k+2)&1][b], s, (unsigned)(k+2));
    }
    {
      float s=wredsum(partdot(W_hh_d + (size_t)grow*H, hbuf, lane));
      if(lane==0) gwhh_l[w]=s;
    }
    {
      float bestv=-FLT_MAX; int besti=0x7fffffff;
      const int nr=rcnt_sh;
      for(int s2=w;s2<nr;s2+=NWAVES){
        const int r=b*LROWS+rlist[s2];
        float s=wredsum(partdot_nt(W_lt + (size_t)r*H, htn_lds, lane));
        if(lane==0){
          float f=s+qbias[rlist[s2]];
          if(f>bestv || (f==bestv && r<besti)){ bestv=f; besti=r; }
        }
      }
      if(lane==0){ redv[w]=bestv; redi[w]=besti; }
    }
    __syncthreads();
    // P15: publish pv candidate
    if(tid==0){
      float bv=redv[0]; int bi=redi[0];
      for(int i=1;i<NWAVES;i++)
        if(redv[i]>bv || (redv[i]==bv && redi[i]<bi)){ bv=redv[i]; bi=redi[i]; }
      pubpv(&g_x.pv[(k+2)&1][b], bv, bi, (unsigned)(k+2));
    }
  }

  // ---- epilogue: last token ----
  if(b==0){
    PVPOLL47((unsigned)(NSTEP+1));
    __syncthreads();
    if(tid==0){
      float bv=redv[4]; int bi=redi[4];
      for(int i=5;i<8;i++)
        if(redv[i]>bv || (redv[i]==bv && redi[i]<bi)){ bv=redv[i]; bi=redi[i]; }
      int iseos=(bi==EOS_ID)?1:0;
      out[NSTEP-1]=(float)((done_sh|iseos)?-1:bi);
    }
  }
#undef PVPOLL47
}

extern "C" void kernel_launch(void* const* d_in, const int* in_sizes, int n_in,
                              void* d_out, int out_size, void* d_ws, size_t ws_size,
                              hipStream_t stream) {
  const int*   src_ids      = (const int*)  d_in[0];
  const float* embed_input  = (const float*)d_in[1];
  const float* W_ih_e       = (const float*)d_in[2];
  const float* W_hh_e       = (const float*)d_in[3];
  const float* b_ih_e       = (const float*)d_in[4];
  const float* b_hh_e       = (const float*)d_in[5];
  const float* W_li         = (const float*)d_in[6];
  const float* b_li         = (const float*)d_in[7];
  const float* embed_target = (const float*)d_in[8];
  const float* W_ih_d       = (const float*)d_in[9];
  const float* W_hh_d       = (const float*)d_in[10];
  const float* b_ih_d       = (const float*)d_in[11];
  const float* b_hh_d       = (const float*)d_in[12];
  const float* W_lt         = (const float*)d_in[13];
  const float* b_lt         = (const float*)d_in[14];
  const float* W_tl         = (const float*)d_in[15];
  const float* b_tl         = (const float*)d_in[16];
  float*       out          = (float*)d_out;

  // zero all tagged slots every launch (tag 0 matches nothing; capture-safe)
  void* sptr = nullptr;
  (void)hipGetSymbolAddress(&sptr, HIP_SYMBOL(g_x));
  if(sptr) (void)hipMemsetAsync(sptr, 0, sizeof(Xch), stream);

  void* argsA[] = {
    (void*)&src_ids, (void*)&embed_input,
    (void*)&W_ih_e, (void*)&W_hh_e, (void*)&b_ih_e, (void*)&b_hh_e
  };
  hipError_t e1 = hipLaunchCooperativeKernel((const void*)nmt_enc,
                                             dim3(NB), dim3(BT), argsA, 0, stream);
  if (e1 != hipSuccess) {
    nmt_enc<<<dim3(NB), dim3(BT), 0, stream>>>(
        src_ids, embed_input, W_ih_e, W_hh_e, b_ih_e, b_hh_e);
  }

  void* argsB[] = {
    (void*)&W_li, (void*)&b_li, (void*)&embed_target,
    (void*)&W_ih_d, (void*)&W_hh_d, (void*)&b_ih_d, (void*)&b_hh_d,
    (void*)&W_lt, (void*)&b_lt, (void*)&W_tl, (void*)&b_tl,
    (void*)&out
  };
  hipError_t e2 = hipLaunchCooperativeKernel((const void*)nmt_dec,
                                             dim3(NB), dim3(BT), argsB,
                                             QTAB_BYTES, stream);
  if (e2 != hipSuccess) {
    nmt_dec<<<dim3(NB), dim3(BT), QTAB_BYTES, stream>>>(
        W_li, b_li, embed_target, W_ih_d, W_hh_d, b_ih_d, b_hh_d,
        W_lt, b_lt, W_tl, b_tl, out);
  }
}